// Round 7
// baseline (286.312 us; speedup 1.0000x reference)
//
#include <hip/hip_runtime.h>

// irreps Linear: out[n, off_l + w*d + i] = 0.125 * sum_u x[n, off_l + u*d + i] * Wl[u][w]
// N=262144 rows of 576 = [64x(d=1) | 64x(d=3) | 64x(d=5)].
// HBM floor ~0.9-1.2 GB @ 6.3 TB/s => ~145-192 us. R3/R5/R6 all tie at ~249 us
// despite different schedules => block-wide barrier+vmcnt(0) coupling caps
// per-CU outstanding memory, not read latency (R6 disproved) or occupancy (R5).
// R7: wave-autonomous pipeline. Block = 1 wave (64 thr), one 16-row tile per
// block, zero cross-wave deps: stage -> MFMA (all 4 w-tiles) -> scatter ->
// copy. Barriers become wave-local drains overlapped by the 7 other resident
// waves/CU (LDS 18432 -> 8 blocks/CU). Accs = 36 f32x4 = 144 VGPR (fits 256
// cap via __launch_bounds__(64,2)); A-frags read once per m-tile, reused 4x.

typedef _Float16 half4  __attribute__((ext_vector_type(4)));
typedef float    f32x4  __attribute__((ext_vector_type(4)));

#define RPB    16                  // rows per tile (= per block)
#define ROWF   576                 // floats per row
#define NROWS  262144
#define NTILES (NROWS / RPB)       // 16384 blocks
#define LDS_B  18432               // x-stage (144 rows x 128 B) = out half-tile (8x576x4)

// ---- stage one l-segment: global f32 -> f16 LDS, rows = (n*D + i), cols = u.
// XOR swizzle (row&7)<<4 breaks the 128B-stride same-bank pattern.
template<int D, int OFF, int SEGROW, int F4PR>   // F4PR = float4s per 576-f row in this seg
__device__ __forceinline__ void stage_seg(unsigned char* lds, const float* __restrict__ xt, int lane) {
#pragma unroll
  for (int it = 0; it < RPB * F4PR / 64; ++it) {  // 4 / 12 / 20 iters
    int t = lane + it * 64;
    int row = t / F4PR;                 // const divisor -> magic mul
    int f4  = t - row * F4PR;
    f32x4 v = *(const f32x4*)(xt + row * ROWF + OFF + f4 * 4);
    int idx = f4 * 4;                   // element index within segment (= u*D + i)
    if (D == 1) {
      int lrow = SEGROW + row;
      int b = (lrow * 128 + idx * 2) ^ ((lrow & 7) << 4);
      half4 h = { (_Float16)v[0], (_Float16)v[1], (_Float16)v[2], (_Float16)v[3] };
      *(half4*)(lds + b) = h;           // 4 consecutive u: one 8B write
    } else {
#pragma unroll
      for (int j = 0; j < 4; ++j) {
        int u = (idx + j) / D;          // const divisor
        int i = (idx + j) - u * D;
        int lrow = SEGROW + row * D + i;
        int b = (lrow * 128 + u * 2) ^ ((lrow & 7) << 4);
        *(_Float16*)(lds + b) = (_Float16)v[j];
      }
    }
  }
}

// B-frags for ALL 4 w-tiles of one l: bf[wt][s][j] = W[s*16+laneq*4+j][wt*16+lane15]
__device__ __forceinline__ void load_bseg(const float* __restrict__ W, int lane15, int laneq,
                                          half4 bf[4][4]) {
#pragma unroll
  for (int wt = 0; wt < 4; ++wt)
#pragma unroll
    for (int s = 0; s < 4; ++s)
#pragma unroll
      for (int j = 0; j < 4; ++j)
        bf[wt][s][j] = (_Float16)W[(s * 16 + laneq * 4 + j) * 64 + wt * 16 + lane15];
}

// one l-segment: read each m-tile's A-frags once, reuse across the 4 w-tiles.
// acc layout: acc[wt*MT + mt]
template<int SEGROW, int MT>
__device__ __forceinline__ void compute_seg(const unsigned char* lds, int lane15, int laneq,
                                            const half4 bf[4][4], f32x4* acc) {
  const int coff = laneq * 8;           // k-chunk byte offset within a row
#pragma unroll
  for (int mt = 0; mt < MT; ++mt) {
    int arow  = SEGROW + mt * 16 + lane15;   // A: m = lane%16, k = s*16 + 4*laneq + j
    int abase = arow * 128;
    int aswz  = (arow & 7) << 4;
    half4 av[4];
#pragma unroll
    for (int s = 0; s < 4; ++s)
      av[s] = *(const half4*)(lds + abase + ((s * 32 + coff) ^ aswz));
#pragma unroll
    for (int wt = 0; wt < 4; ++wt) {
      f32x4 a = acc[wt * MT + mt];
#pragma unroll
      for (int s = 0; s < 4; ++s)
        a = __builtin_amdgcn_mfma_f32_16x16x16f16(av[s], bf[wt][s], a, 0, 0, 0);
      acc[wt * MT + mt] = a;
    }
  }
}

// scatter this half's fragments into the f32 out half-tile ([8][576] row-major)
template<int D, int OFF, int MT, int PHASE>
__device__ __forceinline__ void scatter_seg(unsigned char* lds, int lane15, int laneq,
                                            const f32x4* acc) {
#pragma unroll
  for (int wt = 0; wt < 4; ++wt) {
    int w = wt * 16 + lane15;
#pragma unroll
    for (int mt = 0; mt < MT; ++mt)
#pragma unroll
      for (int j = 0; j < 4; ++j) {
        int r = mt * 16 + laneq * 4 + j;  // D-frag: col = lane&15, row = 4*laneq + j
        int n = r / D;                    // const divisor
        int i = r - n * D;
        bool sel = PHASE ? (n >= 8) : (n < 8);
        if (sel)
          *(float*)(lds + (n - PHASE * 8) * (ROWF * 4) + (OFF + w * D + i) * 4)
              = 0.125f * acc[wt * MT + mt][j];
      }
  }
}

// coalesced copy of one 8x576 f32 half-tile to global: 18 dwordx4 per lane
__device__ __forceinline__ void copy_half(const unsigned char* lds, float* __restrict__ dst, int lane) {
#pragma unroll
  for (int k = 0; k < 18; ++k) {
    int q = lane + k * 64;
    *(f32x4*)(dst + q * 4) = *(const f32x4*)(lds + q * 16);
  }
}

__global__ __launch_bounds__(64, 2) void linear_irreps(
    const float* __restrict__ x,
    const float* __restrict__ w0, const float* __restrict__ w1, const float* __restrict__ w2,
    float* __restrict__ out) {
  __shared__ __align__(16) unsigned char lds[LDS_B];
  const int lane = threadIdx.x;         // block == one wave
  const int lane15 = lane & 15, laneq = lane >> 4;
  const long long base = (long long)blockIdx.x * (RPB * ROWF);
  const float* xt = x + base;

  // stage x tile: 36 KB contiguous span -> f16 LDS [row(n,i)][u], 36 batched dwordx4
  stage_seg<1,   0,  0, 16>(lds, xt, lane);
  stage_seg<3,  64, 16, 48>(lds, xt, lane);
  stage_seg<5, 256, 64, 80>(lds, xt, lane);

  // B-frags per seg (32 VGPR live window each; scheduler hoists under MFMA)
  half4 bf0[4][4], bf1[4][4], bf2[4][4];
  load_bseg(w0, lane15, laneq, bf0);
  load_bseg(w1, lane15, laneq, bf1);
  load_bseg(w2, lane15, laneq, bf2);

  f32x4 acc1[4], acc3[12], acc5[20];    // 36 f32x4 = 144 VGPR
#pragma unroll
  for (int k = 0; k < 4; ++k)  acc1[k] = (f32x4){0.f, 0.f, 0.f, 0.f};
#pragma unroll
  for (int k = 0; k < 12; ++k) acc3[k] = (f32x4){0.f, 0.f, 0.f, 0.f};
#pragma unroll
  for (int k = 0; k < 20; ++k) acc5[k] = (f32x4){0.f, 0.f, 0.f, 0.f};

  __syncthreads();                      // wave-local: LDS writes visible

  compute_seg< 0, 1>(lds, lane15, laneq, bf0, acc1);
  compute_seg<16, 3>(lds, lane15, laneq, bf1, acc3);
  compute_seg<64, 5>(lds, lane15, laneq, bf2, acc5);
  __syncthreads();                      // A-reads done; stage region dead

  // half 0: rows 0..7
  scatter_seg<1,   0, 1, 0>(lds, lane15, laneq, acc1);
  scatter_seg<3,  64, 3, 0>(lds, lane15, laneq, acc3);
  scatter_seg<5, 256, 5, 0>(lds, lane15, laneq, acc5);
  __syncthreads();
  copy_half(lds, out + base, lane);
  __syncthreads();                      // ds_reads done; half region reusable

  // half 1: rows 8..15
  scatter_seg<1,   0, 1, 1>(lds, lane15, laneq, acc1);
  scatter_seg<3,  64, 3, 1>(lds, lane15, laneq, acc3);
  scatter_seg<5, 256, 5, 1>(lds, lane15, laneq, acc5);
  __syncthreads();
  copy_half(lds, out + base + 8 * ROWF, lane);
}

extern "C" void kernel_launch(void* const* d_in, const int* in_sizes, int n_in,
                              void* d_out, int out_size, void* d_ws, size_t ws_size,
                              hipStream_t stream) {
  const float* x  = (const float*)d_in[0];
  const float* w0 = (const float*)d_in[1];
  const float* w1 = (const float*)d_in[2];
  const float* w2 = (const float*)d_in[3];
  float* out = (float*)d_out;
  linear_irreps<<<NTILES, 64, 0, stream>>>(x, w0, w1, w2, out);
}

// Round 8
// 238.421 us; speedup vs baseline: 1.2009x; 1.2009x over previous
//
#include <hip/hip_runtime.h>

// irreps Linear: out[n, off_l + w*d + i] = 0.125 * sum_u x[n, off_l + u*d + i] * Wl[u][w]
// N=262144 rows of 576 = [64x(d=1) | 64x(d=3) | 64x(d=5)].
// R3 (248 us) is the best of 4 schedule variants (R3/R5/R6/R7 = 248/260/249/286)
// => resource-rate ceiling, not scheduling. L2-side 4.87 TB/s = 77% of copy ceiling.
// R8 = R3 + two targeted deltas:
//  (a) XOR involution ((n&7)<<4) on the out-tile LDS addresses: de-overlaps the
//      scatter phase's laneq-group bank collisions (SQ_LDS_BANK_CONFLICT 1.5e7).
//  (b) nontemporal FULL-LINE copy-out stores: out stops evicting x from the
//      256MB L3 (FETCH is already only ~295MB of 604MB x) -> more read hits.
//      (R2's nt disaster was SCALAR nt stores -> partial-line flushes; these
//       are wave-contiguous dwordx4 = full lines.)

typedef _Float16 half4  __attribute__((ext_vector_type(4)));
typedef float    f32x4  __attribute__((ext_vector_type(4)));

#define RPB      16                 // rows per block
#define NROWS    262144
#define ROWF     576                // floats per row
#define OUTBYTES (RPB * ROWF * 4)   // 36864 = out tile f32
#define LDS_BYTES OUTBYTES          // x-stage (18432 B) aliases the same buffer

// ---- stage one l-segment of x into LDS as f16; LDS rows = (n_local*D + i), cols = u.
// XOR swizzle (row&7)<<4 breaks the 128B-stride same-bank pattern.
template<int D, int OFF, int SEGROW, int F4PR>   // F4PR = float4s per 576-f row in this seg
__device__ __forceinline__ void stage_seg(unsigned char* lds, const float* __restrict__ xrow0, int tid) {
#pragma unroll
  for (int it = 0; it < RPB * F4PR / 256; ++it) {  // 1 / 3 / 5 iters, no tail
    int t = tid + it * 256;
    int row = t / F4PR;                 // const divisor -> magic mul
    int f4  = t - row * F4PR;
    f32x4 v = *(const f32x4*)(xrow0 + (long long)row * ROWF + OFF + f4 * 4);
    int idx = f4 * 4;                   // element index within segment (= u*D + i)
    if (D == 1) {
      int lrow = SEGROW + row;
      int b = (lrow * 128 + idx * 2) ^ ((lrow & 7) << 4);
      half4 h = { (_Float16)v[0], (_Float16)v[1], (_Float16)v[2], (_Float16)v[3] };
      *(half4*)(lds + b) = h;           // 4 consecutive u: one 8B write
    } else {
#pragma unroll
      for (int j = 0; j < 4; ++j) {
        int u = (idx + j) / D;          // const divisor
        int i = (idx + j) - u * D;
        int lrow = SEGROW + row * D + i;
        int b = (lrow * 128 + u * 2) ^ ((lrow & 7) << 4);
        *(_Float16*)(lds + b) = (_Float16)v[j];
      }
    }
  }
}

// B-fragments for this wave's wt: bf[s][j] = W[u = s*16 + 4*laneq + j][w = wt*16 + lane15]
__device__ __forceinline__ void load_bfrag(const float* __restrict__ W, int wt,
                                           int lane15, int laneq, half4 bf[4]) {
  int w = wt * 16 + lane15;
#pragma unroll
  for (int s = 0; s < 4; ++s) {
    int u0 = s * 16 + laneq * 4;
#pragma unroll
    for (int j = 0; j < 4; ++j)
      bf[s][j] = (_Float16)W[(u0 + j) * 64 + w];   // 16-lane groups read 64B contig
  }
}

// MFMA all m-tiles of one l-segment for this wave's w-tile
template<int SEGROW, int MT>
__device__ __forceinline__ void compute_seg(const unsigned char* lds, int lane15, int laneq,
                                            const half4 bf[4], f32x4 acc[MT]) {
  const int coff = laneq * 8;           // k-chunk byte offset within a row
#pragma unroll
  for (int mt = 0; mt < MT; ++mt) {
    int arow  = SEGROW + mt * 16 + lane15;   // A: m = lane%16, k = s*16 + 4*laneq + j
    int abase = arow * 128;
    int aswz  = (arow & 7) << 4;
    acc[mt] = (f32x4){0.f, 0.f, 0.f, 0.f};
#pragma unroll
    for (int s = 0; s < 4; ++s) {
      half4 a = *(const half4*)(lds + abase + ((s * 32 + coff) ^ aswz));
      acc[mt] = __builtin_amdgcn_mfma_f32_16x16x16f16(a, bf[s], acc[mt], 0, 0, 0);
    }
  }
}

// scatter acc fragments into the f32 out tile in LDS ([RPB][576] row-major),
// byte addr XOR'd with (n&7)<<4 (involution, un-applied in copy-out): spreads
// the 4 laneq-groups' bank sets apart within each ds_write.
template<int D, int OFF, int MT>
__device__ __forceinline__ void scatter_seg(unsigned char* lds, int wt, int lane15, int laneq,
                                            const f32x4 acc[MT]) {
  const int w = wt * 16 + lane15;
#pragma unroll
  for (int mt = 0; mt < MT; ++mt) {
#pragma unroll
    for (int j = 0; j < 4; ++j) {
      int r = mt * 16 + laneq * 4 + j;  // D-frag: col = lane&15, row = 4*laneq + j
      int n = r / D;                    // const divisor
      int i = r - n * D;
      int b = (n * (ROWF * 4) + (OFF + w * D + i) * 4) ^ ((n & 7) << 4);
      *(float*)(lds + b) = 0.125f * acc[mt][j];
    }
  }
}

__global__ __launch_bounds__(256, 4) void linear_irreps(
    const float* __restrict__ x,
    const float* __restrict__ w0, const float* __restrict__ w1, const float* __restrict__ w2,
    float* __restrict__ out) {
  __shared__ __align__(16) unsigned char lds[LDS_BYTES];
  const int tid = threadIdx.x;
  const int lane = tid & 63, wave = tid >> 6;
  const int lane15 = lane & 15, laneq = lane >> 4;
  const int wt = wave;                  // 4 waves <-> 4 w-tiles (w = wt*16 .. +15)
  const long long base = (long long)blockIdx.x * (RPB * ROWF);

  // weights -> registers (L2-hot; latency overlaps x staging)
  half4 bf0[4], bf1[4], bf2[4];
  load_bfrag(w0, wt, lane15, laneq, bf0);
  load_bfrag(w1, wt, lane15, laneq, bf1);
  load_bfrag(w2, wt, lane15, laneq, bf2);

  // stage x tile (36 KB contiguous global span -> f16 LDS, [row(n,i)][u])
  stage_seg<1,   0,   0, 16>(lds, x + base, tid);
  stage_seg<3,  64,  16, 48>(lds, x + base, tid);
  stage_seg<5, 256,  64, 80>(lds, x + base, tid);
  __syncthreads();

  // MFMA into registers (36 f32 accs/thread)
  f32x4 acc1[1], acc3[3], acc5[5];
  compute_seg<  0, 1>(lds, lane15, laneq, bf0, acc1);
  compute_seg< 16, 3>(lds, lane15, laneq, bf1, acc3);
  compute_seg< 64, 5>(lds, lane15, laneq, bf2, acc5);
  __syncthreads();                      // x-stage region dead before overwrite

  // scatter f32 results into LDS out tile (bank-spread XOR)
  scatter_seg<1,   0, 1>(lds, wt, lane15, laneq, acc1);
  scatter_seg<3,  64, 3>(lds, wt, lane15, laneq, acc3);
  scatter_seg<5, 256, 5>(lds, wt, lane15, laneq, acc5);
  __syncthreads();

  // fully-coalesced copy out: 9 x dwordx4 per thread, nontemporal (full lines;
  // keeps out from evicting x in L3). Un-apply the XOR spread.
#pragma unroll
  for (int k = 0; k < OUTBYTES / 4096; ++k) {      // 9
    int q = tid + k * 256;
    int n = q / 144;                    // 144 float4s per 576-f row
    f32x4 v = *(const f32x4*)(lds + ((q * 16) ^ ((n & 7) << 4)));
    __builtin_nontemporal_store(v, (f32x4*)(out + base + q * 4));
  }
}

extern "C" void kernel_launch(void* const* d_in, const int* in_sizes, int n_in,
                              void* d_out, int out_size, void* d_ws, size_t ws_size,
                              hipStream_t stream) {
  const float* x  = (const float*)d_in[0];
  const float* w0 = (const float*)d_in[1];
  const float* w1 = (const float*)d_in[2];
  const float* w2 = (const float*)d_in[3];
  float* out = (float*)d_out;
  linear_irreps<<<NROWS / RPB, 256, 0, stream>>>(x, w0, w1, w2, out);
}